// Round 6
// baseline (433.460 us; speedup 1.0000x reference)
//
#include <hip/hip_runtime.h>

#define TT 512
#define DD 16
#define HH 48
#define BT 4       // batch rows per block -> 512 blocks, 2 per CU (independent barriers)
#define NTHR 768   // 12 waves: one 16-gate-row tile per wave (192 interleaved gate rows)

typedef short bf8v __attribute__((ext_vector_type(8)));   // 8 x bf16 bits
typedef float f32x4 __attribute__((ext_vector_type(4)));

__device__ __forceinline__ ushort bfb(float f) {
    return __builtin_bit_cast(ushort, (__bf16)f);
}

// y = A*rcp(1+exp2(M*x)) + B  (sigmoid: A=1,M=-log2e,B=0; tanh: A=2,M=-2log2e,B=-1)
__device__ __forceinline__ float actf(float x, float A, float M, float Bc) {
    float e = __builtin_amdgcn_exp2f(M * x);
    return __builtin_fmaf(A, __builtin_amdgcn_rcpf(1.0f + e), Bc);
}

// LDS-only barrier: avoid the vmcnt(0) drain __syncthreads would force (keeps
// the x prefetch global loads in flight across iterations).
__device__ __forceinline__ void barrier_lds() {
    asm volatile("s_waitcnt lgkmcnt(0)\ns_barrier" ::: "memory");
}

__global__ __launch_bounds__(NTHR)
void lstm_kernel(const float* __restrict__ x,
                 const float* __restrict__ Wih0, const float* __restrict__ Whh0,
                 const float* __restrict__ bih0, const float* __restrict__ bhh0,
                 const float* __restrict__ Wih1, const float* __restrict__ Whh1,
                 const float* __restrict__ bih1, const float* __restrict__ bhh1,
                 const float* __restrict__ fcw, const float* __restrict__ fcb,
                 float* __restrict__ out)
{
    // B-operand staging, fragment-order: off(k,n) = (k>>3)*128 + n*8 + (k&7) [ushorts]
    // A0u: L0 input  [x(k0..15) | h1prev(k16..63)],  batch b at col n = b   (b<4)
    // A1u: L1 input  [h1(k0..47) | h2prev(k48..95)], batch b at col n = b+8
    // Cols 4..7 and 12..15 carry bounded junk that provably never reaches real cols.
    __shared__ alignas(16) ushort A0u[2][1024];
    __shared__ alignas(16) ushort A1u[2][1536];
    __shared__ float outl[BT][HH];

    const int tid  = threadIdx.x;
    const int lane = tid & 63;
    const int wave = tid >> 6;
    const int b0   = blockIdx.x * BT;

    const int colq = lane & 15;
    const int quad = lane >> 4;
    const int u    = wave * 4 + quad;     // unit owned in C/D: acc[r] = gate r of unit u
    const bool lo  = (colq < 8);          // lo: L0 cell (batch colq); hi: L1 cell (batch colq-8)

    const int af_o = quad * 128 + colq * 8;    // B-frag read offset (ushorts)
    // combined per-lane h write address into A1[P]:
    //   lo: h1 of batch colq  -> k = u,     col = colq+8
    //   hi: h2 of batch colq-8-> k = 48+u,  col = colq
    const int waddrA1 = lo
        ? ((u >> 3) * 128 + (colq + 8) * 8 + (u & 7))
        : (((48 + u) >> 3) * 128 + colq * 8 + ((48 + u) & 7));
    // lo-only h1prev write into A0[P^1]: k = 16+u, col = colq
    const int wA0 = ((16 + u) >> 3) * 128 + colq * 8 + ((16 + u) & 7);

    const float L2E = 1.4426950408889634f;

    // C-operand biases (all N cols get them; junk cols harmless)
    f32x4 bias0, bias1;
#pragma unroll
    for (int r = 0; r < 4; ++r) {
        bias0[r] = bih0[r * 48 + u] + bhh0[r * 48 + u];
        bias1[r] = bih1[r * 48 + u] + bhh1[r * 48 + u];
    }

    // ---- step-invariant weight A-fragments in registers ----
    // A-frag: lane holds A[m=colq][k=quad*8+j]; interleaved gate row -> PyTorch gi:
    const int gi = (colq & 3) * 48 + wave * 4 + (colq >> 2);
    bf8v w0f0, w0f1, w1f0, w1f1, w1f2;
    {
        bf8v w;
#pragma unroll
        for (int j = 0; j < 8; ++j) {     // L0 k 0..31
            int k = quad * 8 + j;
            float v = (k < 16) ? Wih0[gi * 16 + k] : Whh0[gi * 48 + (k - 16)];
            w[j] = (short)bfb(v);
        }
        w0f0 = w;
#pragma unroll
        for (int j = 0; j < 8; ++j) {     // L0 k 32..63 -> Whh0
            int k = 32 + quad * 8 + j;
            w[j] = (short)bfb(Whh0[gi * 48 + (k - 16)]);
        }
        w0f1 = w;
#pragma unroll
        for (int j = 0; j < 8; ++j) {     // L1 k 0..31 -> Wih1
            int k = quad * 8 + j;
            w[j] = (short)bfb(Wih1[gi * 48 + k]);
        }
        w1f0 = w;
#pragma unroll
        for (int j = 0; j < 8; ++j) {     // L1 k 32..63
            int k = 32 + quad * 8 + j;
            float v = (k < 48) ? Wih1[gi * 48 + k] : Whh1[gi * 48 + (k - 48)];
            w[j] = (short)bfb(v);
        }
        w1f1 = w;
#pragma unroll
        for (int j = 0; j < 8; ++j) {     // L1 k 64..95 -> Whh1
            int k = 64 + quad * 8 + j;
            w[j] = (short)bfb(Whh1[gi * 48 + (k - 48)]);
        }
        w1f2 = w;
    }

    // ---- x staging: wave 11, one float per lane per step (4 rows x 16 d) ----
    const bool stg  = (wave == 11);
    const int  srow = quad;               // batch row 0..3 -> col srow
    const int  sd   = colq;
    const int  sdst = (sd >> 3) * 128 + srow * 8 + (sd & 7);
    const float* sptr = x + (size_t)(b0 + srow) * TT * DD + sd;

    // ---- init: zero both buffers fully (keeps unused cols bounded) ----
    {
        uint* p0 = (uint*)A0u;
        for (int i = tid; i < 1024; i += NTHR) p0[i] = 0;
        uint* p1 = (uint*)A1u;
        for (int i = tid; i < 1536; i += NTHR) p1[i] = 0;
    }
    float r0 = 0.f, r1 = 0.f;
    __syncthreads();
    if (stg) {
        float v = sptr[0];
        r0 = sptr[DD];          // x(1)
        r1 = sptr[2 * DD];      // x(2)
        A0u[0][sdst] = bfb(v);  // x(0)
    }
    __syncthreads();

    float c = 0.f;   // lo: c0 state; hi: c1 state

    // iteration t: L0(t) + L1(t-1); reads A0[P],A1[P^1]; writes A0[P^1],A1[P]; 1 barrier.
    // Staging first: explicit vmcnt(0) guarantees r0/r1 (loads >=1 body old) have
    // landed before the ds_write consumes them (round-4 race fix). The new load
    // then gets a full body of latency hiding before the next barrier.
#define BODY(P, DOL1, t) { \
        if (stg) { \
            asm volatile("s_waitcnt vmcnt(0)" ::: "memory"); \
            A0u[(P)^1][sdst] = bfb(r0); \
            r0 = r1; \
            int t3 = (t) + 3; if (t3 > TT - 1) t3 = TT - 1; \
            r1 = sptr[t3 * DD]; \
        } \
        bf8v a0 = *(const bf8v*)&A0u[P][af_o]; \
        bf8v a1 = *(const bf8v*)&A0u[P][512 + af_o]; \
        f32x4 acc0 = __builtin_amdgcn_mfma_f32_16x16x32_bf16(w0f0, a0, bias0, 0, 0, 0); \
        acc0 = __builtin_amdgcn_mfma_f32_16x16x32_bf16(w0f1, a1, acc0, 0, 0, 0); \
        f32x4 pre; \
        if (DOL1) { \
            bf8v g0 = *(const bf8v*)&A1u[(P)^1][af_o]; \
            bf8v g1 = *(const bf8v*)&A1u[(P)^1][512 + af_o]; \
            bf8v g2 = *(const bf8v*)&A1u[(P)^1][1024 + af_o]; \
            f32x4 acc1 = __builtin_amdgcn_mfma_f32_16x16x32_bf16(w1f0, g0, bias1, 0, 0, 0); \
            acc1 = __builtin_amdgcn_mfma_f32_16x16x32_bf16(w1f1, g1, acc1, 0, 0, 0); \
            acc1 = __builtin_amdgcn_mfma_f32_16x16x32_bf16(w1f2, g2, acc1, 0, 0, 0); \
            pre[0] = lo ? acc0[0] : acc1[0]; \
            pre[1] = lo ? acc0[1] : acc1[1]; \
            pre[2] = lo ? acc0[2] : acc1[2]; \
            pre[3] = lo ? acc0[3] : acc1[3]; \
        } else { \
            pre = acc0; \
        } \
        float iv = actf(pre[0], 1.0f, -L2E, 0.0f); \
        float fv = actf(pre[1], 1.0f, -L2E, 0.0f); \
        float gv = actf(pre[2], 2.0f, -2.0f * L2E, -1.0f); \
        float ov = actf(pre[3], 1.0f, -L2E, 0.0f); \
        float cn = __builtin_fmaf(fv, c, iv * gv); \
        if (!DOL1) cn = lo ? cn : c;   /* peel: don't corrupt L1 state */ \
        c = cn; \
        float tc = actf(cn, 2.0f, -2.0f * L2E, -1.0f); \
        hv = ov * tc; \
        ushort hb = bfb(hv); \
        if (DOL1) { A1u[P][waddrA1] = hb; } \
        else if (lo) { A1u[P][waddrA1] = hb; } \
        if (lo) A0u[(P)^1][wA0] = hb; \
        barrier_lds(); \
    }

    float hv = 0.f;
    BODY(0, false, 0)                       // L0(0) only
    for (int t = 1; t < TT - 1; t += 2) {   // t = 1,3,...,509
        BODY(1, true, t)
        BODY(0, true, t + 1)
    }
    BODY(1, true, TT - 1)                   // t=511: L0(511) + L1(510)

    // post-peel: L1(511) from A1 buffer 1 (written by t=511 body)
    {
        bf8v g0 = *(const bf8v*)&A1u[1][af_o];
        bf8v g1 = *(const bf8v*)&A1u[1][512 + af_o];
        bf8v g2 = *(const bf8v*)&A1u[1][1024 + af_o];
        f32x4 acc1 = __builtin_amdgcn_mfma_f32_16x16x32_bf16(w1f0, g0, bias1, 0, 0, 0);
        acc1 = __builtin_amdgcn_mfma_f32_16x16x32_bf16(w1f1, g1, acc1, 0, 0, 0);
        acc1 = __builtin_amdgcn_mfma_f32_16x16x32_bf16(w1f2, g2, acc1, 0, 0, 0);
        float iv = actf(acc1[0], 1.0f, -L2E, 0.0f);
        float fv = actf(acc1[1], 1.0f, -L2E, 0.0f);
        float gv = actf(acc1[2], 2.0f, -2.0f * L2E, -1.0f);
        float ov = actf(acc1[3], 1.0f, -L2E, 0.0f);
        float cn = __builtin_fmaf(fv, c, iv * gv);
        float tc = actf(cn, 2.0f, -2.0f * L2E, -1.0f);
        hv = ov * tc;                       // valid in hi lanes: h2(511)
    }

    // epilogue: hi lanes colq 8..11 own (batch=colq-8, unit=u) of h2(T-1)
    if (!lo && colq < 8 + BT) outl[colq - 8][u] = hv;
    __syncthreads();
    if (tid < BT) {
        float s = fcb[0];
        for (int uu = 0; uu < HH; ++uu) s = __builtin_fmaf(outl[tid][uu], fcw[uu], s);
        out[b0 + tid] = actf(s, 1.0f, -L2E, 0.0f);
    }
#undef BODY
}

extern "C" void kernel_launch(void* const* d_in, const int* in_sizes, int n_in,
                              void* d_out, int out_size, void* d_ws, size_t ws_size,
                              hipStream_t stream) {
    const float* x    = (const float*)d_in[0];
    const float* Wih0 = (const float*)d_in[1];
    const float* Whh0 = (const float*)d_in[2];
    const float* bih0 = (const float*)d_in[3];
    const float* bhh0 = (const float*)d_in[4];
    const float* Wih1 = (const float*)d_in[5];
    const float* Whh1 = (const float*)d_in[6];
    const float* bih1 = (const float*)d_in[7];
    const float* bhh1 = (const float*)d_in[8];
    const float* fcw  = (const float*)d_in[9];
    const float* fcb  = (const float*)d_in[10];
    lstm_kernel<<<2048 / BT, NTHR, 0, stream>>>(x, Wih0, Whh0, bih0, bhh0,
                                                Wih1, Whh1, bih1, bhh1, fcw, fcb,
                                                (float*)d_out);
}

// Round 7
// 307.702 us; speedup vs baseline: 1.4087x; 1.4087x over previous
//
#include <hip/hip_runtime.h>

#define TT 512
#define DD 16
#define HH 48
#define BT 8       // batch rows per block -> 256 blocks, one per CU (work-efficient point)
#define NTHR 768   // 12 waves; every lane owns exactly one cell (8b x 48u x 2 layers = 768)
#define CHUNK 64   // timesteps of x resident in LDS ring

// LDS layout (ushort units) in one unified array S:
//   [0,      16384) : xbuf  — 64 t-tiles, tile = 256 ushorts, frag order (k=d, col=b)
//   [16384,  17920) : A0h   — h1prev, 2 parities x 6 kgrp x 128  (k=u, col=b)
//   [17920,  20992) : A1    — [h1 | h2prev], 2 parities x 12 kgrp x 128 (cols: b+8 / b+8.. see below)
#define XA0H 16384
#define XA1  17920
#define STOT 20992

typedef short bf8v __attribute__((ext_vector_type(8)));   // 8 x bf16 bits
typedef float f32x4 __attribute__((ext_vector_type(4)));

__device__ __forceinline__ ushort bfb(float f) {
    return __builtin_bit_cast(ushort, (__bf16)f);
}

// y = A*rcp(1+exp2(M*x)) + B  (sigmoid: A=1,M=-log2e,B=0; tanh: A=2,M=-2log2e,B=-1)
__device__ __forceinline__ float actf(float x, float A, float M, float Bc) {
    float e = __builtin_amdgcn_exp2f(M * x);
    return __builtin_fmaf(A, __builtin_amdgcn_rcpf(1.0f + e), Bc);
}

// LDS-only barrier (no global ops are ever in flight across it now)
__device__ __forceinline__ void barrier_lds() {
    asm volatile("s_waitcnt lgkmcnt(0)\ns_barrier" ::: "memory");
}

__global__ __launch_bounds__(NTHR)
void lstm_kernel(const float* __restrict__ x,
                 const float* __restrict__ Wih0, const float* __restrict__ Whh0,
                 const float* __restrict__ bih0, const float* __restrict__ bhh0,
                 const float* __restrict__ Wih1, const float* __restrict__ Whh1,
                 const float* __restrict__ bih1, const float* __restrict__ bhh1,
                 const float* __restrict__ fcw, const float* __restrict__ fcb,
                 float* __restrict__ out)
{
    __shared__ alignas(16) ushort S[STOT];
    __shared__ float outl[BT][HH];

    const int tid  = threadIdx.x;
    const int lane = tid & 63;
    const int wave = tid >> 6;
    const int b0   = blockIdx.x * BT;

    const int colq = lane & 15;
    const int quad = lane >> 4;
    const int u    = wave * 4 + quad;     // unit owned in C/D: acc[r] = gate r of unit u
    const bool lo  = (colq < 8);          // lo: L0 cell (batch colq); hi: L1 cell (batch colq-8)

    const float L2E = 1.4426950408889634f;

    // ---- loop-invariant LDS offsets (ushort units), all in registers ----
    const int fb = colq * 8;                       // fragment col base
    // a0: k0..15 = x (quads 0,1 -> xbuf, advances), k16..31 = h1prev u0..15 (quads 2,3 -> A0h[P])
    const int inc01 = (quad < 2) ? 2 * 256 : 0;    // xbuf advance per body-pair
    // a1: k32..63 = h1prev u16..47 -> A0h kgrp 2..5
    const int a1e = XA0H + (2 + quad) * 128 + fb;
    const int a1o = a1e + 768;
    // g0 (+512 g1, +1024 g2): A1[P^1] kgrp quad / 4+quad / 8+quad
    const int g0e = XA1 + 1536 + quad * 128 + fb;  // even body reads A1[1]
    const int g0o = g0e - 1536;                    // odd body reads A1[0]
    // h1 write into A0h[P^1] (lo lanes): k=u
    const int w0  = (u >> 3) * 128 + fb + (u & 7);
    const int wA0e = XA0H + 768 + w0;
    const int wA0o = XA0H + w0;
    // h write into A1[P]: lo: h1 (k=u, col=colq+8); hi: h2 (k=48+u, col=colq)
    const int wr = lo ? ((u >> 3) * 128 + (colq + 8) * 8 + (u & 7))
                      : (((48 + u) >> 3) * 128 + colq * 8 + ((48 + u) & 7));
    const int wA1e = XA1 + wr;
    const int wA1o = XA1 + 1536 + wr;

    // C-operand biases
    f32x4 bias0, bias1;
#pragma unroll
    for (int r = 0; r < 4; ++r) {
        bias0[r] = bih0[r * 48 + u] + bhh0[r * 48 + u];
        bias1[r] = bih1[r * 48 + u] + bhh1[r * 48 + u];
    }

    // ---- step-invariant weight A-fragments in registers ----
    // A-frag: lane holds A[m=colq][k=quad*8+j]; interleaved gate row -> PyTorch gi:
    const int gi = (colq & 3) * 48 + wave * 4 + (colq >> 2);
    bf8v w0f0, w0f1, w1f0, w1f1, w1f2;
    {
        bf8v w;
#pragma unroll
        for (int j = 0; j < 8; ++j) {     // L0 k 0..31
            int k = quad * 8 + j;
            float v = (k < 16) ? Wih0[gi * 16 + k] : Whh0[gi * 48 + (k - 16)];
            w[j] = (short)bfb(v);
        }
        w0f0 = w;
#pragma unroll
        for (int j = 0; j < 8; ++j) {     // L0 k 32..63 -> Whh0
            int k = 32 + quad * 8 + j;
            w[j] = (short)bfb(Whh0[gi * 48 + (k - 16)]);
        }
        w0f1 = w;
#pragma unroll
        for (int j = 0; j < 8; ++j) {     // L1 k 0..31 -> Wih1
            int k = quad * 8 + j;
            w[j] = (short)bfb(Wih1[gi * 48 + k]);
        }
        w1f0 = w;
#pragma unroll
        for (int j = 0; j < 8; ++j) {     // L1 k 32..63
            int k = 32 + quad * 8 + j;
            float v = (k < 48) ? Wih1[gi * 48 + k] : Whh1[gi * 48 + (k - 48)];
            w[j] = (short)bfb(v);
        }
        w1f1 = w;
#pragma unroll
        for (int j = 0; j < 8; ++j) {     // L1 k 64..95 -> Whh1
            int k = 64 + quad * 8 + j;
            w[j] = (short)bfb(Whh1[gi * 48 + (k - 48)]);
        }
        w1f2 = w;
    }

    // ---- init: zero all of S (junk cols must stay bounded/zero forever) ----
    {
        uint* p = (uint*)S;
        for (int i = tid; i < STOT / 2; i += NTHR) p[i] = 0;
    }
    __syncthreads();

    float c = 0.f;    // lo: c0 state; hi: c1 state
    float hv = 0.f;

    // one body: L0(t) + L1(t-1); 5 ds_read_b128, 5 MFMA, 1 cell, <=2 ds_write_b16, 1 barrier
#define BODY(A0OFF, A1OFF, G0OFF, WA0OFF, WA1OFF, DOL1) { \
        bf8v a0 = *(const bf8v*)&S[A0OFF]; \
        bf8v a1 = *(const bf8v*)&S[A1OFF]; \
        f32x4 acc0 = __builtin_amdgcn_mfma_f32_16x16x32_bf16(w0f0, a0, bias0, 0, 0, 0); \
        acc0 = __builtin_amdgcn_mfma_f32_16x16x32_bf16(w0f1, a1, acc0, 0, 0, 0); \
        f32x4 pre; \
        if (DOL1) { \
            bf8v g0 = *(const bf8v*)&S[G0OFF]; \
            bf8v g1 = *(const bf8v*)&S[(G0OFF) + 512]; \
            bf8v g2 = *(const bf8v*)&S[(G0OFF) + 1024]; \
            f32x4 acc1 = __builtin_amdgcn_mfma_f32_16x16x32_bf16(w1f0, g0, bias1, 0, 0, 0); \
            acc1 = __builtin_amdgcn_mfma_f32_16x16x32_bf16(w1f1, g1, acc1, 0, 0, 0); \
            acc1 = __builtin_amdgcn_mfma_f32_16x16x32_bf16(w1f2, g2, acc1, 0, 0, 0); \
            pre[0] = lo ? acc0[0] : acc1[0]; \
            pre[1] = lo ? acc0[1] : acc1[1]; \
            pre[2] = lo ? acc0[2] : acc1[2]; \
            pre[3] = lo ? acc0[3] : acc1[3]; \
        } else { \
            pre = acc0; \
        } \
        float iv = actf(pre[0], 1.0f, -L2E, 0.0f); \
        float fv = actf(pre[1], 1.0f, -L2E, 0.0f); \
        float gv = actf(pre[2], 2.0f, -2.0f * L2E, -1.0f); \
        float ov = actf(pre[3], 1.0f, -L2E, 0.0f); \
        float cn = __builtin_fmaf(fv, c, iv * gv); \
        if (!DOL1) cn = lo ? cn : c;   /* peel: don't corrupt L1 state */ \
        c = cn; \
        float tc = actf(cn, 2.0f, -2.0f * L2E, -1.0f); \
        hv = ov * tc; \
        ushort hb = bfb(hv); \
        if (DOL1) { S[WA1OFF] = hb; } \
        else if (lo) { S[WA1OFF] = hb; } \
        if (lo) S[WA0OFF] = hb; \
        barrier_lds(); \
    }

    for (int ck = 0; ck < TT / CHUNK; ++ck) {
        // ---- refill x ring for t in [ck*64, ck*64+64): coalesced, all waves ----
        for (int i = tid; i < BT * CHUNK * 4; i += NTHR) {   // 2048 float4 rows
            int g  = i & 3;
            int tl = (i >> 2) & (CHUNK - 1);
            int b  = i >> 8;
            const float4 v = *(const float4*)(x +
                ((size_t)(b0 + b) * TT + (ck * CHUNK + tl)) * DD + g * 4);
            ushort4 s4;
            s4.x = bfb(v.x); s4.y = bfb(v.y); s4.z = bfb(v.z); s4.w = bfb(v.w);
            *(ushort4*)&S[tl * 256 + (g >> 1) * 128 + b * 8 + (g & 1) * 4] = s4;
        }
        __syncthreads();   // full drain: no persistent global loads exist

        // mixed a0 addresses for this chunk (quads 0,1 -> xbuf; 2,3 -> A0h[P])
        int ae = (quad < 2) ? (quad * 128 + fb) : (XA0H + (quad - 2) * 128 + fb);
        int ao = (quad < 2) ? (256 + quad * 128 + fb) : (XA0H + 768 + (quad - 2) * 128 + fb);

        int p0 = 0;
        if (ck == 0) {   // peel: body 0 has no L1 yet
            BODY(ae, a1e, g0e, wA0e, wA1e, false)
            BODY(ao, a1o, g0o, wA0o, wA1o, true)
            ae += inc01; ao += inc01;
            p0 = 1;
        }
        for (int p = p0; p < CHUNK / 2; ++p) {
            BODY(ae, a1e, g0e, wA0e, wA1e, true)
            BODY(ao, a1o, g0o, wA0o, wA1o, true)
            ae += inc01; ao += inc01;
        }
    }

    // post-peel: L1(511) from A1[1] (t=511 was an odd body writing A1[1])
    {
        bf8v g0 = *(const bf8v*)&S[g0e];
        bf8v g1 = *(const bf8v*)&S[g0e + 512];
        bf8v g2 = *(const bf8v*)&S[g0e + 1024];
        f32x4 acc1 = __builtin_amdgcn_mfma_f32_16x16x32_bf16(w1f0, g0, bias1, 0, 0, 0);
        acc1 = __builtin_amdgcn_mfma_f32_16x16x32_bf16(w1f1, g1, acc1, 0, 0, 0);
        acc1 = __builtin_amdgcn_mfma_f32_16x16x32_bf16(w1f2, g2, acc1, 0, 0, 0);
        float iv = actf(acc1[0], 1.0f, -L2E, 0.0f);
        float fv = actf(acc1[1], 1.0f, -L2E, 0.0f);
        float gv = actf(acc1[2], 2.0f, -2.0f * L2E, -1.0f);
        float ov = actf(acc1[3], 1.0f, -L2E, 0.0f);
        float cn = __builtin_fmaf(fv, c, iv * gv);
        float tc = actf(cn, 2.0f, -2.0f * L2E, -1.0f);
        hv = ov * tc;                       // valid in hi lanes: h2(511)
    }

    // epilogue: hi lanes own (batch=colq-8, unit=u) of h2(T-1)
    if (!lo) outl[colq - 8][u] = hv;
    __syncthreads();
    if (tid < BT) {
        float s = fcb[0];
        for (int uu = 0; uu < HH; ++uu) s = __builtin_fmaf(outl[tid][uu], fcw[uu], s);
        out[b0 + tid] = actf(s, 1.0f, -L2E, 0.0f);
    }
#undef BODY
}

extern "C" void kernel_launch(void* const* d_in, const int* in_sizes, int n_in,
                              void* d_out, int out_size, void* d_ws, size_t ws_size,
                              hipStream_t stream) {
    const float* x    = (const float*)d_in[0];
    const float* Wih0 = (const float*)d_in[1];
    const float* Whh0 = (const float*)d_in[2];
    const float* bih0 = (const float*)d_in[3];
    const float* bhh0 = (const float*)d_in[4];
    const float* Wih1 = (const float*)d_in[5];
    const float* Whh1 = (const float*)d_in[6];
    const float* bih1 = (const float*)d_in[7];
    const float* bhh1 = (const float*)d_in[8];
    const float* fcw  = (const float*)d_in[9];
    const float* fcb  = (const float*)d_in[10];
    lstm_kernel<<<2048 / BT, NTHR, 0, stream>>>(x, Wih0, Whh0, bih0, bhh0,
                                                Wih1, Whh1, bih1, bhh1, fcw, fcb,
                                                (float*)d_out);
}